// Round 6
// baseline (386.273 us; speedup 1.0000x reference)
//
#include <hip/hip_runtime.h>

// GraphSAGE 3-layer, N=50000, E=1.6M, D=128.
// R11: aggregate-FIRST restructure (matches the reference's own order):
//      m = mean of gathered bf16(h) rows (exact hi/lo bf16 pair), then ONE
//      fused gemm per layer: out = act(h@Ws^T + m@Wn^T + b). Kills the
//      y_self 25MB fp32 write+read round-trip (agg fetch 165->~120MB) and
//      the per-layer z buffer; gemm A-operands are pre-split hi/lo planes
//      (no VALU split except layer-1 x). bucket_scan merged into bucket_csr;
//      gcursor zero via hipMemsetAsync. Same absmax profile (one bf16
//      rounding in the neighbor path, as before).

constexpr int N_NODES = 50000;
constexpr int N_EDGES = 1600000;
constexpr int D = 128;
constexpr int NTILES = N_NODES / 16;          // 3125 (exact)

constexpr int NBUCK = 392;                    // ceil(50176/128) node-range buckets
constexpr int BCAP  = 6144;                   // capacity per bucket (mean 4082)
constexpr int EPB   = 4096;                   // edges per block in count/scatter
constexpr int CS_BLOCKS = (N_EDGES + EPB - 1) / EPB;   // 391
constexpr int GC_STRIDE = 16;                 // 64B pad: 1 atomic counter per sector

constexpr int NT  = 8;                        // src tiles (tp layout)
constexpr int TSH = 13;                       // tile = src >> 13

typedef __bf16 bf16x8 __attribute__((ext_vector_type(8)));
typedef float f32x4 __attribute__((ext_vector_type(4)));
union U8 { bf16x8 v; __bf16 e[8]; };

// ---------------- bucket count + scatter ----------------------------------
__global__ __launch_bounds__(256) void bucket_count_scatter(
        const int* __restrict__ dst, const int* __restrict__ src,
        int* __restrict__ gcursor, int* __restrict__ bucketbuf) {
    __shared__ int hcnt[NBUCK];
    __shared__ int hbase[NBUCK];
    const int tid = threadIdx.x;
    for (int i = tid; i < NBUCK; i += 256) hcnt[i] = 0;
    __syncthreads();

    const int e0 = blockIdx.x * EPB;
    int d[16], lp[16];
    #pragma unroll
    for (int t = 0; t < 16; ++t) {
        const int e = e0 + t * 256 + tid;
        if (e < N_EDGES) {
            d[t] = dst[e];
            lp[t] = atomicAdd(&hcnt[d[t] >> 7], 1);   // LDS atomic, local pos
        } else {
            d[t] = 0; lp[t] = -1;
        }
    }
    __syncthreads();

    for (int i = tid; i < NBUCK; i += 256) {
        const int c = hcnt[i];
        hbase[i] = c ? atomicAdd(&gcursor[i * GC_STRIDE], c) : 0;  // 1/(blk,bucket)
    }
    __syncthreads();

    #pragma unroll
    for (int t = 0; t < 16; ++t) {
        const int e = e0 + t * 256 + tid;
        if (e < N_EDGES) {
            const int s  = src[e];
            const int bk = d[t] >> 7;
            const int p  = hbase[bk] + lp[t];
            if (p < BCAP)
                bucketbuf[bk * BCAP + p] = ((d[t] & 127) << 16) | s;
        }
    }
}

// ---------------- per-bucket CSR finalize (scan merged in) -----------------
// One block per bucket. base = sum of counts of buckets < bk (block-local
// reduction over gcursor, replaces the separate bucket_scan kernel). Then
// LDS hist of 128 nodes x 8 src-tiles -> tp[node*8+t] + inv_deg, then
// LDS-cursor scatter of esrc grouped by (node, tile).
__global__ __launch_bounds__(256) void bucket_csr(
        const int* __restrict__ gcursor, const int* __restrict__ bucketbuf,
        int* __restrict__ tp, float* __restrict__ inv_deg,
        int* __restrict__ esrc) {
    __shared__ int h[1024];
    __shared__ int cur[1024];
    __shared__ int wsum[4], wpre[4];
    __shared__ int redw[4];
    const int bk = blockIdx.x, tid = threadIdx.x;
    int cnt = gcursor[bk * GC_STRIDE];
    if (cnt > BCAP) cnt = BCAP;

    // ---- base = prefix sum over buckets < bk (reduction) ----
    int partial = 0;
    for (int i = tid; i < bk; i += 256) {
        int v = gcursor[i * GC_STRIDE];
        partial += (v > BCAP ? BCAP : v);
    }
    #pragma unroll
    for (int off = 32; off; off >>= 1) partial += __shfl_down(partial, off, 64);
    if ((tid & 63) == 0) redw[tid >> 6] = partial;

    #pragma unroll
    for (int k = 0; k < 4; ++k) h[tid * 4 + k] = 0;
    __syncthreads();
    const int base = redw[0] + redw[1] + redw[2] + redw[3];

    const int* bb = bucketbuf + (size_t)bk * BCAP;
    for (int i = tid; i < cnt; i += 256) {
        const int p = bb[i];
        atomicAdd(&h[((p >> 16) << 3) | ((p & 0xFFFF) >> TSH)], 1);
    }
    __syncthreads();

    if (tid < 128) {
        int dg = 0;
        #pragma unroll
        for (int k = 0; k < 8; ++k) dg += h[tid * 8 + k];
        inv_deg[bk * 128 + tid] = 1.0f / fmaxf((float)dg, 1.0f);
    }

    // exclusive scan of 1024 counters (4 per thread)
    const int v0 = h[tid * 4], v1 = h[tid * 4 + 1];
    const int v2 = h[tid * 4 + 2], v3 = h[tid * 4 + 3];
    const int s = v0 + v1 + v2 + v3;
    int x = s;
    const int lane = tid & 63, w = tid >> 6;
    #pragma unroll
    for (int off = 1; off < 64; off <<= 1) {
        int tt = __shfl_up(x, off, 64);
        if (lane >= off) x += tt;
    }
    if (lane == 63) wsum[w] = x;
    __syncthreads();
    if (tid == 0) {
        int a = 0;
        #pragma unroll
        for (int k = 0; k < 4; ++k) { wpre[k] = a; a += wsum[k]; }
    }
    __syncthreads();
    const int e0 = wpre[w] + (x - s);
    const int e1 = e0 + v0, e2 = e1 + v1, e3 = e2 + v2;
    cur[tid * 4] = e0; cur[tid * 4 + 1] = e1;
    cur[tid * 4 + 2] = e2; cur[tid * 4 + 3] = e3;
    int* tpo = tp + (size_t)bk * 1024 + tid * 4;
    tpo[0] = base + e0; tpo[1] = base + e1; tpo[2] = base + e2; tpo[3] = base + e3;
    __syncthreads();

    for (int i = tid; i < cnt; i += 256) {
        const int p = bb[i];
        const int f = ((p >> 16) << 3) | ((p & 0xFFFF) >> TSH);
        esrc[base + atomicAdd(&cur[f], 1)] = p & 0xFFFF;
    }
}

// ---------------- pack W into MFMA B-fragment order, hi+lo ---------------
__global__ void pack_w(const float* __restrict__ w0, const float* __restrict__ w1,
                       const float* __restrict__ w2, const float* __restrict__ w3,
                       const float* __restrict__ w4, const float* __restrict__ w5,
                       __bf16* __restrict__ outbase) {
    const float* ws[6] = {w0, w1, w2, w3, w4, w5};
    const float* W = ws[blockIdx.y];
    __bf16* o = outbase + (size_t)blockIdx.y * 32768;
    int idx = blockIdx.x * 256 + threadIdx.x;   // 0..16383
    int t = idx & 7;
    int lane = (idx >> 3) & 63;
    int ks = (idx >> 9) & 3;
    int jt = idx >> 11;
    int j = jt * 16 + (lane & 15);
    int k = ks * 32 + (lane >> 4) * 8 + t;
    float w = W[j * D + k];
    __bf16 hi = (__bf16)w;
    o[idx] = hi;
    o[16384 + idx] = (__bf16)(w - (float)hi);
}

// ---------------- split x -> bf16 hi plane (for layer-1 gather) ----------
__global__ __launch_bounds__(256) void split_x(const float* __restrict__ x,
                                               __bf16* __restrict__ xh, int n8) {
    const int i = blockIdx.x * 256 + threadIdx.x;
    if (i < n8) {
        const float* p = x + (size_t)i * 8;
        const f32x4 a = *(const f32x4*)p;
        const f32x4 b = *(const f32x4*)(p + 4);
        U8 h;
        #pragma unroll
        for (int k = 0; k < 4; ++k) { h.e[k] = (__bf16)a[k]; h.e[4 + k] = (__bf16)b[k]; }
        *(bf16x8*)(xh + (size_t)i * 8) = h.v;
    }
}

// ---------------- aggregate-first: m = mean of gathered h rows ------------
// R5's proven gather loop (wave/node, 4 slots x 16 lanes x 16B, 16 loads in
// flight), but NO y_self read: writes the mean as an exact hi/lo bf16 pair.
__global__ __launch_bounds__(256) void agg_mean(
        const __bf16* __restrict__ hplane, const int* __restrict__ esrc,
        const int* __restrict__ tp, const float* __restrict__ inv_deg,
        __bf16* __restrict__ m_hi, __bf16* __restrict__ m_lo) {
    const int n = blockIdx.x * 4 + (threadIdx.x >> 6);
    const int lane = threadIdx.x & 63;
    const int s = lane >> 4;
    const int c = lane & 15;
    const int r0 = tp[n * NT], r1 = tp[(n + 1) * NT];

    float acc[8] = {0.f, 0.f, 0.f, 0.f, 0.f, 0.f, 0.f, 0.f};
    int e = r0 + s;
    for (; e + 12 < r1; e += 16) {
        int i0 = esrc[e], i1 = esrc[e + 4], i2 = esrc[e + 8], i3 = esrc[e + 12];
        U8 v0, v1, v2, v3;
        v0.v = *(const bf16x8*)(hplane + (size_t)i0 * D + c * 8);
        v1.v = *(const bf16x8*)(hplane + (size_t)i1 * D + c * 8);
        v2.v = *(const bf16x8*)(hplane + (size_t)i2 * D + c * 8);
        v3.v = *(const bf16x8*)(hplane + (size_t)i3 * D + c * 8);
        #pragma unroll
        for (int t = 0; t < 8; ++t)
            acc[t] += ((float)v0.e[t] + (float)v1.e[t]) + ((float)v2.e[t] + (float)v3.e[t]);
    }
    for (; e < r1; e += 4) {
        U8 v0;
        v0.v = *(const bf16x8*)(hplane + (size_t)esrc[e] * D + c * 8);
        #pragma unroll
        for (int t = 0; t < 8; ++t) acc[t] += (float)v0.e[t];
    }
    #pragma unroll
    for (int t = 0; t < 8; ++t) acc[t] += __shfl_down(acc[t], 32, 64);
    #pragma unroll
    for (int t = 0; t < 8; ++t) acc[t] += __shfl_down(acc[t], 16, 64);

    if (lane < 16) {
        const float idg = inv_deg[n];
        U8 mh, ml;
        #pragma unroll
        for (int t = 0; t < 8; ++t) {
            const float mm = acc[t] * idg;
            const __bf16 hi = (__bf16)mm;
            mh.e[t] = hi;
            ml.e[t] = (__bf16)(mm - (float)hi);
        }
        *(bf16x8*)(m_hi + (size_t)n * D + c * 8) = mh.v;
        *(bf16x8*)(m_lo + (size_t)n * D + c * 8) = ml.v;
    }
}

// ---------------- fused gemm: out = act(h@Ws^T + m@Wn^T + b) --------------
// One wave per 16-row tile (R5 occupancy). A-operands: layer 1 reads x fp32
// and splits in VALU; layers 2-3 read pre-split hi/lo planes. Output:
// layers 1-2 write relu'd hi/lo pair; layer 3 writes fp32.
__global__ __launch_bounds__(256) void fused_gemm(
        const float* __restrict__ x32,
        const __bf16* __restrict__ a_hi, const __bf16* __restrict__ a_lo,
        const __bf16* __restrict__ m_hi, const __bf16* __restrict__ m_lo,
        const __bf16* __restrict__ Bs, const __bf16* __restrict__ Bn,
        const float* __restrict__ bias,
        __bf16* __restrict__ o_hi, __bf16* __restrict__ o_lo,
        float* __restrict__ o32) {
    const int wave = threadIdx.x >> 6;
    const int lane = threadIdx.x & 63;
    const int tile = blockIdx.x * 4 + wave;
    if (tile >= NTILES) return;
    const int n0 = tile * 16;
    const int row = n0 + (lane & 15);
    const int koff = (lane >> 4) * 8;

    U8 ah[4], al[4], mh[4], ml[4];
    if (x32) {
        #pragma unroll
        for (int ks = 0; ks < 4; ++ks) {
            const float* p = x32 + (size_t)row * D + ks * 32 + koff;
            float f[8];
            *(f32x4*)&f[0] = *(const f32x4*)p;
            *(f32x4*)&f[4] = *(const f32x4*)(p + 4);
            #pragma unroll
            for (int t = 0; t < 8; ++t) {
                const __bf16 hi = (__bf16)f[t];
                ah[ks].e[t] = hi;
                al[ks].e[t] = (__bf16)(f[t] - (float)hi);
            }
        }
    } else {
        #pragma unroll
        for (int ks = 0; ks < 4; ++ks) {
            ah[ks].v = *(const bf16x8*)(a_hi + (size_t)row * D + ks * 32 + koff);
            al[ks].v = *(const bf16x8*)(a_lo + (size_t)row * D + ks * 32 + koff);
        }
    }
    #pragma unroll
    for (int ks = 0; ks < 4; ++ks) {
        mh[ks].v = *(const bf16x8*)(m_hi + (size_t)row * D + ks * 32 + koff);
        ml[ks].v = *(const bf16x8*)(m_lo + (size_t)row * D + ks * 32 + koff);
    }

    const int jcol = lane & 15;
    const int r0q = (lane >> 4) * 4;

    #pragma unroll 2
    for (int jt = 0; jt < 8; ++jt) {
        f32x4 accS = {0.f, 0.f, 0.f, 0.f};
        f32x4 accN = {0.f, 0.f, 0.f, 0.f};
        #pragma unroll
        for (int ks = 0; ks < 4; ++ks) {
            const size_t off = (((size_t)jt * 4 + ks) * 64 + lane) * 8;
            const bf16x8 wsh = *(const bf16x8*)(Bs + off);
            const bf16x8 wsl = *(const bf16x8*)(Bs + 16384 + off);
            const bf16x8 wnh = *(const bf16x8*)(Bn + off);
            const bf16x8 wnl = *(const bf16x8*)(Bn + 16384 + off);
            accS = __builtin_amdgcn_mfma_f32_16x16x32_bf16(ah[ks].v, wsh, accS, 0, 0, 0);
            accS = __builtin_amdgcn_mfma_f32_16x16x32_bf16(al[ks].v, wsh, accS, 0, 0, 0);
            accS = __builtin_amdgcn_mfma_f32_16x16x32_bf16(ah[ks].v, wsl, accS, 0, 0, 0);
            accN = __builtin_amdgcn_mfma_f32_16x16x32_bf16(mh[ks].v, wnh, accN, 0, 0, 0);
            accN = __builtin_amdgcn_mfma_f32_16x16x32_bf16(ml[ks].v, wnh, accN, 0, 0, 0);
            accN = __builtin_amdgcn_mfma_f32_16x16x32_bf16(mh[ks].v, wnl, accN, 0, 0, 0);
        }
        const int j = jt * 16 + jcol;
        const float bj = bias[j];
        if (o32) {
            #pragma unroll
            for (int r = 0; r < 4; ++r) {
                const size_t n = n0 + r0q + r;
                o32[n * D + j] = accS[r] + accN[r] + bj;
            }
        } else {
            #pragma unroll
            for (int r = 0; r < 4; ++r) {
                const size_t n = n0 + r0q + r;
                float o = fmaxf(accS[r] + accN[r] + bj, 0.f);
                const __bf16 hi = (__bf16)o;
                o_hi[n * D + j] = hi;
                o_lo[n * D + j] = (__bf16)(o - (float)hi);
            }
        }
    }
}

extern "C" void kernel_launch(void* const* d_in, const int* in_sizes, int n_in,
                              void* d_out, int out_size, void* d_ws, size_t ws_size,
                              hipStream_t stream) {
    const float* x   = (const float*)d_in[0];
    const int* src   = (const int*)d_in[1];
    const int* dst   = (const int*)d_in[2];
    const float* Wn1 = (const float*)d_in[3];
    const float* Ws1 = (const float*)d_in[4];
    const float* b1  = (const float*)d_in[5];
    const float* Wn2 = (const float*)d_in[6];
    const float* Ws2 = (const float*)d_in[7];
    const float* b2  = (const float*)d_in[8];
    const float* Wn3 = (const float*)d_in[9];
    const float* Ws3 = (const float*)d_in[10];
    const float* b3  = (const float*)d_in[11];
    float* out = (float*)d_out;

    constexpr size_t PLANE = (size_t)50176 * D * 2;  // 12.85 MB bf16 plane

    char* w = (char*)d_ws;
    float* inv_deg = (float*)w;                 w += 50176 * 4;
    int* tp        = (int*)w;                   w += (size_t)NBUCK * 1024 * 4;
    int* gcursor   = (int*)w;                   w += NBUCK * GC_STRIDE * 4;
    int* esrc      = (int*)w;                   w += (size_t)N_EDGES * 4;
    __bf16* Bpk    = (__bf16*)w;                w += 6 * 32768 * 2;
    __bf16* xh     = (__bf16*)w;                w += PLANE;
    __bf16* mhi    = (__bf16*)w;                w += PLANE;
    __bf16* mlo    = (__bf16*)w;                w += PLANE;
    __bf16* pAh    = (__bf16*)w;                w += PLANE;
    __bf16* pAl    = (__bf16*)w;                w += PLANE;
    __bf16* pBh    = (__bf16*)w;                w += PLANE;
    __bf16* pBl    = (__bf16*)w;                // last plane

    // bucketbuf (9.63MB) aliases pBh (12.85MB): consumed by bucket_csr long
    // before fused_gemm(layer 2) first writes pBh (stream-ordered).
    int* bucketbuf = (int*)pBh;

    const __bf16* PWs1 = Bpk + 0 * 32768, *PWn1 = Bpk + 1 * 32768;
    const __bf16* PWs2 = Bpk + 2 * 32768, *PWn2 = Bpk + 3 * 32768;
    const __bf16* PWs3 = Bpk + 4 * 32768, *PWn3 = Bpk + 5 * 32768;

    // ---- CSR build ----
    hipMemsetAsync(gcursor, 0, NBUCK * GC_STRIDE * 4, stream);
    bucket_count_scatter<<<CS_BLOCKS, 256, 0, stream>>>(dst, src, gcursor, bucketbuf);
    bucket_csr<<<NBUCK, 256, 0, stream>>>(gcursor, bucketbuf, tp, inv_deg, esrc);

    // ---- weight pack + x hi-plane ----
    pack_w<<<dim3(64, 6), 256, 0, stream>>>(Ws1, Wn1, Ws2, Wn2, Ws3, Wn3, Bpk);
    split_x<<<(N_NODES * D / 8 + 255) / 256, 256, 0, stream>>>(x, xh, N_NODES * D / 8);

    const int ggrid = (NTILES + 3) / 4;         // 782 blocks x 4 waves
    const int agrid = N_NODES / 4;              // 12500 blocks x 4 waves

    // layer 1: m = mean(xh); pA = relu(x@Ws1 + m@Wn1 + b1)
    agg_mean<<<agrid, 256, 0, stream>>>(xh, esrc, tp, inv_deg, mhi, mlo);
    fused_gemm<<<ggrid, 256, 0, stream>>>(x, nullptr, nullptr, mhi, mlo,
                                          PWs1, PWn1, b1, pAh, pAl, nullptr);

    // layer 2: m = mean(pAh); pB = relu(pA@Ws2 + m@Wn2 + b2)
    agg_mean<<<agrid, 256, 0, stream>>>(pAh, esrc, tp, inv_deg, mhi, mlo);
    fused_gemm<<<ggrid, 256, 0, stream>>>(nullptr, pAh, pAl, mhi, mlo,
                                          PWs2, PWn2, b2, pBh, pBl, nullptr);

    // layer 3: m = mean(pBh); out = pB@Ws3 + m@Wn3 + b3 (fp32, no relu)
    agg_mean<<<agrid, 256, 0, stream>>>(pBh, esrc, tp, inv_deg, mhi, mlo);
    fused_gemm<<<ggrid, 256, 0, stream>>>(nullptr, pBh, pBl, mhi, mlo,
                                          PWs3, PWn3, b3, nullptr, nullptr, out);
}